// Round 1
// baseline (159.771 us; speedup 1.0000x reference)
//
#include <hip/hip_runtime.h>
#include <math.h>

#define B_ 8
#define C_ 64
#define N_ 4096

// ws float layout:
// [0, 512)            colsum[b][c]
// [512, 33280)        G[b][c][c']   (8*64*64)
// [33280, 33792)      a[b][o]       (scale_b * alpha_o)
// [33792, 34304)      bb[b][o]      ((q-mean)*alpha + beta)

// ---------------------------------------------------------------------------
// Kernel 1: per-batch Gram matrix G[b] = X X^T (over n) + colsum, tiled over n.
// grid (32, 8): x = n-tile (Tk=128), y = b. 256 threads.
// ---------------------------------------------------------------------------
__global__ __launch_bounds__(256) void k_gram(const float* __restrict__ x,
                                              float* __restrict__ ws) {
    const int kt = blockIdx.x;   // n-tile, 128 wide
    const int b  = blockIdx.y;
    const int t  = threadIdx.x;

    __shared__ float xs[128 * 65];   // [k][c] transposed, stride 65 (pad)

    float* colsum = ws;              // [8][64]
    float* G      = ws + 512;        // [8][64][64]

    const float* xb = x + (size_t)b * C_ * N_ + (size_t)kt * 128;

    // Load 64 rows x 128 cols of x, store transposed into xs[k][c].
    // thread t: k = (t%32)*4 (float4), row c = it*8 + t/32
    const int k0 = (t & 31) * 4;
    #pragma unroll
    for (int it = 0; it < 8; ++it) {
        const int cc = it * 8 + (t >> 5);
        const float4 v = *reinterpret_cast<const float4*>(xb + (size_t)cc * N_ + k0);
        xs[(k0 + 0) * 65 + cc] = v.x;
        xs[(k0 + 1) * 65 + cc] = v.y;
        xs[(k0 + 2) * 65 + cc] = v.z;
        xs[(k0 + 3) * 65 + cc] = v.w;
        // fold colsum: 32 lanes of each half-wave share cc
        float s4 = v.x + v.y + v.z + v.w;
        #pragma unroll
        for (int m = 16; m >= 1; m >>= 1) s4 += __shfl_xor(s4, m, 32);
        if ((t & 31) == 0) atomicAdd(&colsum[b * 64 + cc], s4);
    }
    __syncthreads();

    // 4x4 register tile per thread over the 64x64 Gram output.
    const int c1 = (t >> 4) * 4;   // 0..60
    const int c2 = (t & 15) * 4;   // 0..60
    float acc[4][4] = {};
    for (int k = 0; k < 128; ++k) {
        const float* row = &xs[k * 65];
        const float a0 = row[c1 + 0], a1 = row[c1 + 1], a2 = row[c1 + 2], a3 = row[c1 + 3];
        const float b0 = row[c2 + 0], b1 = row[c2 + 1], b2 = row[c2 + 2], b3 = row[c2 + 3];
        acc[0][0] += a0 * b0; acc[0][1] += a0 * b1; acc[0][2] += a0 * b2; acc[0][3] += a0 * b3;
        acc[1][0] += a1 * b0; acc[1][1] += a1 * b1; acc[1][2] += a1 * b2; acc[1][3] += a1 * b3;
        acc[2][0] += a2 * b0; acc[2][1] += a2 * b1; acc[2][2] += a2 * b2; acc[2][3] += a2 * b3;
        acc[3][0] += a3 * b0; acc[3][1] += a3 * b1; acc[3][2] += a3 * b2; acc[3][3] += a3 * b3;
    }
    float* Gb = &G[(size_t)b * 64 * 64];
    #pragma unroll
    for (int i = 0; i < 4; ++i)
        #pragma unroll
        for (int j = 0; j < 4; ++j)
            atomicAdd(&Gb[(c1 + i) * 64 + (c2 + j)], acc[i][j]);
}

// ---------------------------------------------------------------------------
// Kernel 2: per-output-channel BN statistics via the Gram trick; writes the
// folded per-(b,o) affine (a, bb). grid 64 (one block per o), 256 threads.
// ---------------------------------------------------------------------------
__global__ __launch_bounds__(256) void k_finalize(const float* __restrict__ wvec,
                                                  const float* __restrict__ conv_w,
                                                  const float* __restrict__ conv_b,
                                                  const float* __restrict__ gamma,
                                                  const float* __restrict__ beta,
                                                  float* __restrict__ ws) {
    const int o = blockIdx.x;
    const int t = threadIdx.x;

    __shared__ float red[256];
    __shared__ float sS[8], sScale[8];
    __shared__ float Wrow[64];
    __shared__ float Tq[8], Qq[8];

    // s_b = sum relu(tanh(w))^2 (redundant per block; w is tiny + L2-hot)
    for (int b = 0; b < 8; ++b) {
        float p = 0.f;
        for (int n = t; n < N_; n += 256) {
            const float v = wvec[b * N_ + n];
            if (v > 0.f) { const float th = tanhf(v); p += th * th; }
        }
        red[t] = p;
        __syncthreads();
        for (int s = 128; s >= 1; s >>= 1) {
            if (t < s) red[t] += red[t + s];
            __syncthreads();
        }
        if (t == 0) {
            sS[b]     = red[0];
            sScale[b] = 1.f / ((float)N_ * red[0] + 1.f);
        }
        __syncthreads();
    }

    if (t < 64) Wrow[t] = conv_w[o * 64 + t];
    __syncthreads();

    // Traw[b] = W_o . colsum[b], Qraw[b] = W_o^T G_b W_o
    // 512 (b,c) rows over 256 threads; wave wv reduces b=wv (h=0), b=wv+4 (h=1)
    float pT[2], pQ[2];
    #pragma unroll
    for (int h = 0; h < 2; ++h) {
        const int r = t + h * 256;
        const int b = r >> 6, c = r & 63;
        const float* Grow = ws + 512 + ((size_t)(b * 64 + c)) * 64;
        float dot = 0.f;
        for (int cc = 0; cc < 64; ++cc) dot += Wrow[cc] * Grow[cc];
        pQ[h] = Wrow[c] * dot;
        pT[h] = Wrow[c] * ws[b * 64 + c];
    }
    #pragma unroll
    for (int m = 32; m >= 1; m >>= 1) {
        pQ[0] += __shfl_xor(pQ[0], m);
        pQ[1] += __shfl_xor(pQ[1], m);
        pT[0] += __shfl_xor(pT[0], m);
        pT[1] += __shfl_xor(pT[1], m);
    }
    if ((t & 63) == 0) {
        const int wv = t >> 6;
        Tq[wv] = pT[0]; Qq[wv] = pQ[0];
        Tq[wv + 4] = pT[1]; Qq[wv + 4] = pQ[1];
    }
    __syncthreads();

    if (t == 0) {
        float Sy = 0.f, Syy = 0.f;
        float qv[8];
        #pragma unroll
        for (int b = 0; b < 8; ++b) {
            const float sc = sScale[b];
            const float T  = sc * Tq[b];               // sum_n z[b,o,:]
            const float q  = sS[b] * T + conv_b[o];    // per-(b,o) constant
            qv[b] = q;
            Sy  += T + 4096.f * q;
            Syy += sc * sc * Qq[b] + 2.f * q * T + 4096.f * q * q;
        }
        const float mean  = Sy / 32768.f;
        const float var   = Syy / 32768.f - mean * mean;
        const float alpha = gamma[o] * rsqrtf(var + 1e-5f);
        #pragma unroll
        for (int b = 0; b < 8; ++b) {
            ws[33280 + b * 64 + o] = sScale[b] * alpha;
            ws[33792 + b * 64 + o] = (qv[b] - mean) * alpha + beta[o];
        }
    }
}

// ---------------------------------------------------------------------------
// Kernel 3: out = relu(a[b,o] * (W x)[o,n] + bb[b,o]).
// grid (32, 8): x = n-tile (128 wide), y = b. 256 threads.
// Per thread: 8 o x 4 n register tile.
// ---------------------------------------------------------------------------
__global__ __launch_bounds__(256) void k_main(const float* __restrict__ x,
                                              const float* __restrict__ conv_w,
                                              const float* __restrict__ ws,
                                              float* __restrict__ out) {
    const int nt = blockIdx.x;
    const int b  = blockIdx.y;
    const int t  = threadIdx.x;

    __shared__ float xsm[64 * 128];  // [c][n] 32KB
    __shared__ float Wt[64 * 64];    // [c][o] 16KB, pre-scaled by a[b][o]

    const int n0 = nt * 128;
    const float* xb = x + (size_t)b * C_ * N_ + n0;

    // W transposed + folded with a[b][o]
    #pragma unroll
    for (int it = 0; it < 16; ++it) {
        const int e = it * 256 + t;
        const int o = e >> 6, c = e & 63;
        Wt[c * 64 + o] = conv_w[e] * ws[33280 + b * 64 + o];
    }
    // x tile
    const int k0 = (t & 31) * 4;
    #pragma unroll
    for (int it = 0; it < 8; ++it) {
        const int cc = it * 8 + (t >> 5);
        *reinterpret_cast<float4*>(&xsm[cc * 128 + k0]) =
            *reinterpret_cast<const float4*>(xb + (size_t)cc * N_ + k0);
    }

    const int o0 = (t >> 5) * 8;   // 8 o per thread
    const int nn = (t & 31) * 4;   // 4 n per thread
    float bias[8];
    #pragma unroll
    for (int i = 0; i < 8; ++i) bias[i] = ws[33792 + b * 64 + o0 + i];
    __syncthreads();

    float acc[8][4] = {};
    for (int c = 0; c < 64; ++c) {
        const float4 xv = *reinterpret_cast<const float4*>(&xsm[c * 128 + nn]);
        const float4 w0 = *reinterpret_cast<const float4*>(&Wt[c * 64 + o0]);
        const float4 w1 = *reinterpret_cast<const float4*>(&Wt[c * 64 + o0 + 4]);
        acc[0][0] += w0.x * xv.x; acc[0][1] += w0.x * xv.y; acc[0][2] += w0.x * xv.z; acc[0][3] += w0.x * xv.w;
        acc[1][0] += w0.y * xv.x; acc[1][1] += w0.y * xv.y; acc[1][2] += w0.y * xv.z; acc[1][3] += w0.y * xv.w;
        acc[2][0] += w0.z * xv.x; acc[2][1] += w0.z * xv.y; acc[2][2] += w0.z * xv.z; acc[2][3] += w0.z * xv.w;
        acc[3][0] += w0.w * xv.x; acc[3][1] += w0.w * xv.y; acc[3][2] += w0.w * xv.z; acc[3][3] += w0.w * xv.w;
        acc[4][0] += w1.x * xv.x; acc[4][1] += w1.x * xv.y; acc[4][2] += w1.x * xv.z; acc[4][3] += w1.x * xv.w;
        acc[5][0] += w1.y * xv.x; acc[5][1] += w1.y * xv.y; acc[5][2] += w1.y * xv.z; acc[5][3] += w1.y * xv.w;
        acc[6][0] += w1.z * xv.x; acc[6][1] += w1.z * xv.y; acc[6][2] += w1.z * xv.z; acc[6][3] += w1.z * xv.w;
        acc[7][0] += w1.w * xv.x; acc[7][1] += w1.w * xv.y; acc[7][2] += w1.w * xv.z; acc[7][3] += w1.w * xv.w;
    }

    #pragma unroll
    for (int i = 0; i < 8; ++i) {
        const int o = o0 + i;
        float4 r;
        r.x = fmaxf(acc[i][0] + bias[i], 0.f);
        r.y = fmaxf(acc[i][1] + bias[i], 0.f);
        r.z = fmaxf(acc[i][2] + bias[i], 0.f);
        r.w = fmaxf(acc[i][3] + bias[i], 0.f);
        *reinterpret_cast<float4*>(out + ((size_t)(b * 64 + o)) * N_ + n0 + nn) = r;
    }
}

extern "C" void kernel_launch(void* const* d_in, const int* in_sizes, int n_in,
                              void* d_out, int out_size, void* d_ws, size_t ws_size,
                              hipStream_t stream) {
    (void)in_sizes; (void)n_in; (void)out_size; (void)ws_size;
    const float* x      = (const float*)d_in[0];
    const float* w      = (const float*)d_in[1];
    const float* conv_w = (const float*)d_in[2];
    const float* conv_b = (const float*)d_in[3];
    const float* gamma  = (const float*)d_in[4];
    const float* beta   = (const float*)d_in[5];
    float* out = (float*)d_out;
    float* ws  = (float*)d_ws;

    // zero the atomic accumulation region (colsum + G)
    hipMemsetAsync(ws, 0, (512 + 8 * 64 * 64) * sizeof(float), stream);

    k_gram<<<dim3(32, 8), 256, 0, stream>>>(x, ws);
    k_finalize<<<64, 256, 0, stream>>>(w, conv_w, conv_b, gamma, beta, ws);
    k_main<<<dim3(32, 8), 256, 0, stream>>>(x, conv_w, ws, out);
}

// Round 2
// 120.423 us; speedup vs baseline: 1.3267x; 1.3267x over previous
//
#include <hip/hip_runtime.h>
#include <math.h>

#define B_ 8
#define C_ 64
#define N_ 4096

// ws float layout:
// [0, 512)            colsum[b][c]
// [512, 33280)        G[b][c][c']   (8*64*64)
// [33280, 33792)      a[b][o]       (scale_b * alpha_o)
// [33792, 34304)      bb[b][o]      ((q-mean)*alpha + beta)
// [34304, 34312)      sS[b]         (s_b = sum relu(tanh(w))^2)
// [34312, 34320)      sScale[b]     (1/(N*s_b+1))

// ---------------------------------------------------------------------------
// Kernel 0: per-batch scalar s_b. grid 8, 256 threads.
// ---------------------------------------------------------------------------
__global__ __launch_bounds__(256) void k_scales(const float* __restrict__ wvec,
                                                float* __restrict__ ws) {
    const int b = blockIdx.x;
    const int t = threadIdx.x;
    const float4* wb = reinterpret_cast<const float4*>(wvec + (size_t)b * N_);
    float p = 0.f;
    #pragma unroll
    for (int i = 0; i < 4; ++i) {
        const float4 v = wb[t + i * 256];
        const float vv[4] = {v.x, v.y, v.z, v.w};
        #pragma unroll
        for (int j = 0; j < 4; ++j) {
            if (vv[j] > 0.f) { const float th = tanhf(vv[j]); p += th * th; }
        }
    }
    #pragma unroll
    for (int m = 32; m >= 1; m >>= 1) p += __shfl_xor(p, m);
    __shared__ float red[4];
    if ((t & 63) == 0) red[t >> 6] = p;
    __syncthreads();
    if (t == 0) {
        const float s = red[0] + red[1] + red[2] + red[3];
        ws[34304 + b] = s;
        ws[34312 + b] = 1.f / ((float)N_ * s + 1.f);
    }
}

// ---------------------------------------------------------------------------
// Kernel 1: per-batch Gram matrix G[b] = X X^T (over n) + colsum.
// grid (8, 8): x = n-chunk (512 wide), y = b. 256 threads.
// Each block loops over 4 sub-tiles of 128 n, acc stays in registers.
// ---------------------------------------------------------------------------
__global__ __launch_bounds__(256) void k_gram(const float* __restrict__ x,
                                              float* __restrict__ ws) {
    const int chunk = blockIdx.x;   // 512-wide n-chunk
    const int b     = blockIdx.y;
    const int t     = threadIdx.x;

    __shared__ float xs[128 * 65];  // [k][c] transposed, stride 65 (pad)

    float* colsum = ws;             // [8][64]
    float* G      = ws + 512;       // [8][64][64]

    const float* xb = x + (size_t)b * C_ * N_ + (size_t)chunk * 512;

    const int k0 = (t & 31) * 4;
    const int c1 = (t >> 4) * 4;    // Gram row group
    const int c2 = (t & 15) * 4;    // Gram col group

    float acc[4][4] = {};
    float csum[8] = {};

    for (int s = 0; s < 4; ++s) {
        if (s) __syncthreads();
        // load 64 rows x 128 cols, transposed into xs[k][c]
        #pragma unroll
        for (int it = 0; it < 8; ++it) {
            const int cc = it * 8 + (t >> 5);
            const float4 v = *reinterpret_cast<const float4*>(
                xb + (size_t)cc * N_ + s * 128 + k0);
            xs[(k0 + 0) * 65 + cc] = v.x;
            xs[(k0 + 1) * 65 + cc] = v.y;
            xs[(k0 + 2) * 65 + cc] = v.z;
            xs[(k0 + 3) * 65 + cc] = v.w;
            csum[it] += v.x + v.y + v.z + v.w;
        }
        __syncthreads();

        for (int k = 0; k < 128; ++k) {
            const float* row = &xs[k * 65];
            const float a0 = row[c1 + 0], a1 = row[c1 + 1], a2 = row[c1 + 2], a3 = row[c1 + 3];
            const float b0 = row[c2 + 0], b1 = row[c2 + 1], b2 = row[c2 + 2], b3 = row[c2 + 3];
            acc[0][0] += a0 * b0; acc[0][1] += a0 * b1; acc[0][2] += a0 * b2; acc[0][3] += a0 * b3;
            acc[1][0] += a1 * b0; acc[1][1] += a1 * b1; acc[1][2] += a1 * b2; acc[1][3] += a1 * b3;
            acc[2][0] += a2 * b0; acc[2][1] += a2 * b1; acc[2][2] += a2 * b2; acc[2][3] += a2 * b3;
            acc[3][0] += a3 * b0; acc[3][1] += a3 * b1; acc[3][2] += a3 * b2; acc[3][3] += a3 * b3;
        }
    }

    // colsum: reduce within each half-wave (lanes share cc), one atomic each
    #pragma unroll
    for (int it = 0; it < 8; ++it) {
        float s4 = csum[it];
        #pragma unroll
        for (int m = 16; m >= 1; m >>= 1) s4 += __shfl_xor(s4, m, 32);
        if ((t & 31) == 0) atomicAdd(&colsum[b * 64 + it * 8 + (t >> 5)], s4);
    }

    float* Gb = &G[(size_t)b * 64 * 64];
    #pragma unroll
    for (int i = 0; i < 4; ++i)
        #pragma unroll
        for (int j = 0; j < 4; ++j)
            atomicAdd(&Gb[(c1 + i) * 64 + (c2 + j)], acc[i][j]);
}

// ---------------------------------------------------------------------------
// Kernel 2: per-output-channel BN statistics via the Gram trick; writes the
// folded per-(b,o) affine (a, bb). grid 64 (one block per o), 256 threads.
// ---------------------------------------------------------------------------
__global__ __launch_bounds__(256) void k_finalize(const float* __restrict__ conv_w,
                                                  const float* __restrict__ conv_b,
                                                  const float* __restrict__ gamma,
                                                  const float* __restrict__ beta,
                                                  float* __restrict__ ws) {
    const int o = blockIdx.x;
    const int t = threadIdx.x;

    __shared__ float Wrow[64];
    __shared__ float Tq[8], Qq[8];

    if (t < 64) Wrow[t] = conv_w[o * 64 + t];
    __syncthreads();

    // Traw[b] = W_o . colsum[b], Qraw[b] = W_o^T G_b W_o
    // 512 (b,c) rows over 256 threads; wave wv reduces b=wv (h=0), b=wv+4 (h=1)
    float pT[2], pQ[2];
    #pragma unroll
    for (int h = 0; h < 2; ++h) {
        const int r = t + h * 256;
        const int b = r >> 6, c = r & 63;
        const float* Grow = ws + 512 + ((size_t)(b * 64 + c)) * 64;
        float dot = 0.f;
        #pragma unroll 8
        for (int cc = 0; cc < 64; ++cc) dot += Wrow[cc] * Grow[cc];
        pQ[h] = Wrow[c] * dot;
        pT[h] = Wrow[c] * ws[b * 64 + c];
    }
    #pragma unroll
    for (int m = 32; m >= 1; m >>= 1) {
        pQ[0] += __shfl_xor(pQ[0], m);
        pQ[1] += __shfl_xor(pQ[1], m);
        pT[0] += __shfl_xor(pT[0], m);
        pT[1] += __shfl_xor(pT[1], m);
    }
    if ((t & 63) == 0) {
        const int wv = t >> 6;
        Tq[wv] = pT[0]; Qq[wv] = pQ[0];
        Tq[wv + 4] = pT[1]; Qq[wv + 4] = pQ[1];
    }
    __syncthreads();

    if (t == 0) {
        float Sy = 0.f, Syy = 0.f;
        float qv[8];
        #pragma unroll
        for (int b = 0; b < 8; ++b) {
            const float sS = ws[34304 + b];
            const float sc = ws[34312 + b];
            const float T  = sc * Tq[b];               // sum_n z[b,o,:]
            const float q  = sS * T + conv_b[o];       // per-(b,o) constant
            qv[b] = q;
            Sy  += T + 4096.f * q;
            Syy += sc * sc * Qq[b] + 2.f * q * T + 4096.f * q * q;
        }
        const float mean  = Sy / 32768.f;
        const float var   = Syy / 32768.f - mean * mean;
        const float alpha = gamma[o] * rsqrtf(var + 1e-5f);
        #pragma unroll
        for (int b = 0; b < 8; ++b) {
            const float sc = ws[34312 + b];
            ws[33280 + b * 64 + o] = sc * alpha;
            ws[33792 + b * 64 + o] = (qv[b] - mean) * alpha + beta[o];
        }
    }
}

// ---------------------------------------------------------------------------
// Kernel 3: out = relu(a[b,o] * (W x)[o,n] + bb[b,o]).
// grid (32, 8): x = n-tile (128 wide), y = b. 256 threads.
// Per thread: 8 o x 4 n register tile.
// ---------------------------------------------------------------------------
__global__ __launch_bounds__(256) void k_main(const float* __restrict__ x,
                                              const float* __restrict__ conv_w,
                                              const float* __restrict__ ws,
                                              float* __restrict__ out) {
    const int nt = blockIdx.x;
    const int b  = blockIdx.y;
    const int t  = threadIdx.x;

    __shared__ float xsm[64 * 128];  // [c][n] 32KB
    __shared__ float Wt[64 * 64];    // [c][o] 16KB, pre-scaled by a[b][o]

    const int n0 = nt * 128;
    const float* xb = x + (size_t)b * C_ * N_ + n0;

    // W transposed + folded with a[b][o]
    #pragma unroll
    for (int it = 0; it < 16; ++it) {
        const int e = it * 256 + t;
        const int o = e >> 6, c = e & 63;
        Wt[c * 64 + o] = conv_w[e] * ws[33280 + b * 64 + o];
    }
    // x tile
    const int k0 = (t & 31) * 4;
    #pragma unroll
    for (int it = 0; it < 8; ++it) {
        const int cc = it * 8 + (t >> 5);
        *reinterpret_cast<float4*>(&xsm[cc * 128 + k0]) =
            *reinterpret_cast<const float4*>(xb + (size_t)cc * N_ + k0);
    }

    const int o0 = (t >> 5) * 8;   // 8 o per thread
    const int nn = (t & 31) * 4;   // 4 n per thread
    float bias[8];
    #pragma unroll
    for (int i = 0; i < 8; ++i) bias[i] = ws[33792 + b * 64 + o0 + i];
    __syncthreads();

    float acc[8][4] = {};
    for (int c = 0; c < 64; ++c) {
        const float4 xv = *reinterpret_cast<const float4*>(&xsm[c * 128 + nn]);
        const float4 w0 = *reinterpret_cast<const float4*>(&Wt[c * 64 + o0]);
        const float4 w1 = *reinterpret_cast<const float4*>(&Wt[c * 64 + o0 + 4]);
        acc[0][0] += w0.x * xv.x; acc[0][1] += w0.x * xv.y; acc[0][2] += w0.x * xv.z; acc[0][3] += w0.x * xv.w;
        acc[1][0] += w0.y * xv.x; acc[1][1] += w0.y * xv.y; acc[1][2] += w0.y * xv.z; acc[1][3] += w0.y * xv.w;
        acc[2][0] += w0.z * xv.x; acc[2][1] += w0.z * xv.y; acc[2][2] += w0.z * xv.z; acc[2][3] += w0.z * xv.w;
        acc[3][0] += w0.w * xv.x; acc[3][1] += w0.w * xv.y; acc[3][2] += w0.w * xv.z; acc[3][3] += w0.w * xv.w;
        acc[4][0] += w1.x * xv.x; acc[4][1] += w1.x * xv.y; acc[4][2] += w1.x * xv.z; acc[4][3] += w1.x * xv.w;
        acc[5][0] += w1.y * xv.x; acc[5][1] += w1.y * xv.y; acc[5][2] += w1.y * xv.z; acc[5][3] += w1.y * xv.w;
        acc[6][0] += w1.z * xv.x; acc[6][1] += w1.z * xv.y; acc[6][2] += w1.z * xv.z; acc[6][3] += w1.z * xv.w;
        acc[7][0] += w1.w * xv.x; acc[7][1] += w1.w * xv.y; acc[7][2] += w1.w * xv.z; acc[7][3] += w1.w * xv.w;
    }

    #pragma unroll
    for (int i = 0; i < 8; ++i) {
        const int o = o0 + i;
        float4 r;
        r.x = fmaxf(acc[i][0] + bias[i], 0.f);
        r.y = fmaxf(acc[i][1] + bias[i], 0.f);
        r.z = fmaxf(acc[i][2] + bias[i], 0.f);
        r.w = fmaxf(acc[i][3] + bias[i], 0.f);
        *reinterpret_cast<float4*>(out + ((size_t)(b * 64 + o)) * N_ + n0 + nn) = r;
    }
}

extern "C" void kernel_launch(void* const* d_in, const int* in_sizes, int n_in,
                              void* d_out, int out_size, void* d_ws, size_t ws_size,
                              hipStream_t stream) {
    (void)in_sizes; (void)n_in; (void)out_size; (void)ws_size;
    const float* x      = (const float*)d_in[0];
    const float* w      = (const float*)d_in[1];
    const float* conv_w = (const float*)d_in[2];
    const float* conv_b = (const float*)d_in[3];
    const float* gamma  = (const float*)d_in[4];
    const float* beta   = (const float*)d_in[5];
    float* out = (float*)d_out;
    float* ws  = (float*)d_ws;

    // zero the atomic accumulation region (colsum + G)
    hipMemsetAsync(ws, 0, (512 + 8 * 64 * 64) * sizeof(float), stream);

    k_scales<<<8, 256, 0, stream>>>(w, ws);
    k_gram<<<dim3(8, 8), 256, 0, stream>>>(x, ws);
    k_finalize<<<64, 256, 0, stream>>>(conv_w, conv_b, gamma, beta, ws);
    k_main<<<dim3(32, 8), 256, 0, stream>>>(x, conv_w, ws, out);
}

// Round 4
// 103.347 us; speedup vs baseline: 1.5460x; 1.1652x over previous
//
#include <hip/hip_runtime.h>
#include <math.h>

#define B_ 8
#define C_ 64
#define N_ 4096
#define NT_ 32   // n-tiles (128 wide) in k_gram

// ws float offsets
#define GP_OFF  0                         // Gp[tile][b][64][64] partial Grams (4 MB)
#define CSP_OFF (NT_ * B_ * C_ * C_)      // colsum_p[tile][b][64]
#define G_OFF   (CSP_OFF + NT_ * B_ * C_) // G[b][64][64] reduced
#define CS_OFF  (G_OFF + B_ * C_ * C_)    // colsum[b][64]
#define SS_OFF  (CS_OFF + B_ * C_)        // sS[b]
#define SC_OFF  (SS_OFF + B_)             // sScale[b] = 1/(N*s+1)
#define A_OFF   (SC_OFF + B_)             // a[b][o] = sScale_b * alpha_o
#define BB_OFF  (A_OFF + B_ * C_)         // bb[b][o]

// ---------------------------------------------------------------------------
// Kernel 1: partial Gram Gp[tile][b] = X_tile X_tile^T + partial colsum.
// grid (33, 8): x<32 = 128-wide n-tile; x==32 = fused per-batch scales block.
// 256 threads. No atomics, no pre-zero needed anywhere.
// ---------------------------------------------------------------------------
__global__ __launch_bounds__(256) void k_gram(const float* __restrict__ x,
                                              const float* __restrict__ wvec,
                                              float* __restrict__ ws) {
    const int b = blockIdx.y;
    const int t = threadIdx.x;

    __shared__ float xs[128 * 65];   // [k][c] transposed, stride 65

    if (blockIdx.x == NT_) {
        // fused scales: s_b = sum relu(tanh(w))^2
        const float4* wb = reinterpret_cast<const float4*>(wvec + (size_t)b * N_);
        float p = 0.f;
        #pragma unroll
        for (int i = 0; i < 4; ++i) {
            const float4 v = wb[t + i * 256];
            const float vv[4] = {v.x, v.y, v.z, v.w};
            #pragma unroll
            for (int j = 0; j < 4; ++j)
                if (vv[j] > 0.f) { const float th = tanhf(vv[j]); p += th * th; }
        }
        #pragma unroll
        for (int m = 32; m >= 1; m >>= 1) p += __shfl_xor(p, m);
        if ((t & 63) == 0) xs[t >> 6] = p;
        __syncthreads();
        if (t == 0) {
            const float s = xs[0] + xs[1] + xs[2] + xs[3];
            ws[SS_OFF + b] = s;
            ws[SC_OFF + b] = 1.f / ((float)N_ * s + 1.f);
        }
        return;
    }

    const int tile = blockIdx.x;
    const float* xb = x + (size_t)b * C_ * N_ + (size_t)tile * 128;

    // load 64 rows x 128 cols transposed into xs[k][c]; fold colsum in regs
    const int k0 = (t & 31) * 4;
    float csum[8];
    #pragma unroll
    for (int it = 0; it < 8; ++it) {
        const int cc = it * 8 + (t >> 5);
        const float4 v = *reinterpret_cast<const float4*>(xb + (size_t)cc * N_ + k0);
        xs[(k0 + 0) * 65 + cc] = v.x;
        xs[(k0 + 1) * 65 + cc] = v.y;
        xs[(k0 + 2) * 65 + cc] = v.z;
        xs[(k0 + 3) * 65 + cc] = v.w;
        csum[it] = v.x + v.y + v.z + v.w;
    }
    __syncthreads();

    // 4x4 register tile over 64x64 Gram (A/B reads are broadcast: conflict-free)
    const int c1 = (t >> 4) * 4;
    const int c2 = (t & 15) * 4;
    float acc[4][4] = {};
    for (int k = 0; k < 128; ++k) {
        const float* row = &xs[k * 65];
        const float a0 = row[c1 + 0], a1 = row[c1 + 1], a2 = row[c1 + 2], a3 = row[c1 + 3];
        const float b0 = row[c2 + 0], b1 = row[c2 + 1], b2 = row[c2 + 2], b3 = row[c2 + 3];
        acc[0][0] += a0 * b0; acc[0][1] += a0 * b1; acc[0][2] += a0 * b2; acc[0][3] += a0 * b3;
        acc[1][0] += a1 * b0; acc[1][1] += a1 * b1; acc[1][2] += a1 * b2; acc[1][3] += a1 * b3;
        acc[2][0] += a2 * b0; acc[2][1] += a2 * b1; acc[2][2] += a2 * b2; acc[2][3] += a2 * b3;
        acc[3][0] += a3 * b0; acc[3][1] += a3 * b1; acc[3][2] += a3 * b2; acc[3][3] += a3 * b3;
    }

    // partial colsum (one plain store per half-wave, no atomics)
    #pragma unroll
    for (int it = 0; it < 8; ++it) {
        float s4 = csum[it];
        #pragma unroll
        for (int m = 16; m >= 1; m >>= 1) s4 += __shfl_xor(s4, m, 32);
        if ((t & 31) == 0)
            ws[CSP_OFF + (tile * B_ + b) * C_ + it * 8 + (t >> 5)] = s4;
    }

    // partial Gram: coalesced float4 stores into this block's private slot
    float* Gp = ws + GP_OFF + (size_t)(tile * B_ + b) * (C_ * C_);
    #pragma unroll
    for (int i = 0; i < 4; ++i) {
        float4 r;
        r.x = acc[i][0]; r.y = acc[i][1]; r.z = acc[i][2]; r.w = acc[i][3];
        *reinterpret_cast<float4*>(&Gp[(c1 + i) * 64 + c2]) = r;
    }
}

// ---------------------------------------------------------------------------
// Kernel 2: reduce the 32 partials -> G[b], colsum[b]. grid 64, 256 threads.
// block = (b, 8-row slice). 4 MB of L2-hot reads total.
// ---------------------------------------------------------------------------
__global__ __launch_bounds__(256) void k_reduce(float* __restrict__ ws) {
    const int blk = blockIdx.x;
    const int b = blk >> 3, slice = blk & 7;
    const int t = threadIdx.x;

    #pragma unroll
    for (int h = 0; h < 2; ++h) {
        const int e = h * 256 + t;                // 0..511
        const int c = slice * 8 + (e >> 6);
        const int cc = e & 63;
        float s = 0.f;
        #pragma unroll 8
        for (int p = 0; p < NT_; ++p)
            s += ws[GP_OFF + (size_t)(p * B_ + b) * (C_ * C_) + c * 64 + cc];
        ws[G_OFF + (size_t)b * (C_ * C_) + c * 64 + cc] = s;
    }
    if (slice == 0 && t < 64) {
        float s = 0.f;
        #pragma unroll 8
        for (int p = 0; p < NT_; ++p)
            s += ws[CSP_OFF + (p * B_ + b) * C_ + t];
        ws[CS_OFF + b * 64 + t] = s;
    }
}

// ---------------------------------------------------------------------------
// Kernel 3: BN statistics via the Gram trick -> per-(b,o) affine (a, bb).
// grid 64 (one block per o), 256 threads.
// ---------------------------------------------------------------------------
__global__ __launch_bounds__(256) void k_finalize(const float* __restrict__ conv_w,
                                                  const float* __restrict__ conv_b,
                                                  const float* __restrict__ gamma,
                                                  const float* __restrict__ beta,
                                                  float* __restrict__ ws) {
    const int o = blockIdx.x;
    const int t = threadIdx.x;

    __shared__ float Wrow[64];
    __shared__ float Tq[8], Qq[8];

    if (t < 64) Wrow[t] = conv_w[o * 64 + t];
    __syncthreads();

    // Traw[b] = W_o . colsum[b], Qraw[b] = W_o^T G_b W_o
    float pT[2], pQ[2];
    #pragma unroll
    for (int h = 0; h < 2; ++h) {
        const int r = t + h * 256;
        const int bb = r >> 6, c = r & 63;
        const float* Grow = ws + G_OFF + ((size_t)(bb * 64 + c)) * 64;
        float dot = 0.f;
        #pragma unroll 8
        for (int cc = 0; cc < 64; ++cc) dot += Wrow[cc] * Grow[cc];
        pQ[h] = Wrow[c] * dot;
        pT[h] = Wrow[c] * ws[CS_OFF + bb * 64 + c];
    }
    #pragma unroll
    for (int m = 32; m >= 1; m >>= 1) {
        pQ[0] += __shfl_xor(pQ[0], m);
        pQ[1] += __shfl_xor(pQ[1], m);
        pT[0] += __shfl_xor(pT[0], m);
        pT[1] += __shfl_xor(pT[1], m);
    }
    if ((t & 63) == 0) {
        const int wv = t >> 6;
        Tq[wv] = pT[0]; Qq[wv] = pQ[0];
        Tq[wv + 4] = pT[1]; Qq[wv + 4] = pQ[1];
    }
    __syncthreads();

    if (t == 0) {
        float Sy = 0.f, Syy = 0.f;
        float qv[8];
        #pragma unroll
        for (int b = 0; b < 8; ++b) {
            const float sS = ws[SS_OFF + b];
            const float sc = ws[SC_OFF + b];
            const float T  = sc * Tq[b];
            const float q  = sS * T + conv_b[o];
            qv[b] = q;
            Sy  += T + 4096.f * q;
            Syy += sc * sc * Qq[b] + 2.f * q * T + 4096.f * q * q;
        }
        const float mean  = Sy / 32768.f;
        const float var   = Syy / 32768.f - mean * mean;
        const float alpha = gamma[o] * rsqrtf(var + 1e-5f);
        #pragma unroll
        for (int b = 0; b < 8; ++b) {
            ws[A_OFF  + b * 64 + o] = ws[SC_OFF + b] * alpha;
            ws[BB_OFF + b * 64 + o] = (qv[b] - mean) * alpha + beta[o];
        }
    }
}

// ---------------------------------------------------------------------------
// Kernel 4: out = relu(a[b,o] * (W x)[o,n] + bb[b,o]).
// grid (32, 8), 512 threads (8 waves). W read via wave-uniform scalar loads
// (L2-hot 16 KB) — no W LDS tile, no transposed-store bank conflicts.
// Per thread: 8 o x 2 n.
// ---------------------------------------------------------------------------
__global__ __launch_bounds__(512) void k_main(const float* __restrict__ x,
                                              const float* __restrict__ conv_w,
                                              const float* __restrict__ ws,
                                              float* __restrict__ out) {
    const int nt = blockIdx.x;
    const int b  = blockIdx.y;
    const int t  = threadIdx.x;

    __shared__ float xsm[64 * 128];   // [c][n] 32 KB

    const int n0 = nt * 128;
    const float* xb = x + (size_t)b * C_ * N_ + n0;

    // stage x tile (coalesced float4, conflict-free stores along n)
    const int k0 = (t & 31) * 4;
    #pragma unroll
    for (int it = 0; it < 4; ++it) {
        const int cc = it * 16 + (t >> 5);
        *reinterpret_cast<float4*>(&xsm[cc * 128 + k0]) =
            *reinterpret_cast<const float4*>(xb + (size_t)cc * N_ + k0);
    }

    const int o0 = __builtin_amdgcn_readfirstlane((t >> 6) * 8);  // wave-uniform
    const int nn = (t & 63) * 2;

    float au[8], bu[8];
    #pragma unroll
    for (int i = 0; i < 8; ++i) {
        au[i] = ws[A_OFF  + b * 64 + o0 + i];
        bu[i] = ws[BB_OFF + b * 64 + o0 + i];
    }
    __syncthreads();

    float acc[8][2] = {};
    #pragma unroll 4
    for (int c = 0; c < 64; ++c) {
        const float2 xv = *reinterpret_cast<const float2*>(&xsm[c * 128 + nn]);
        #pragma unroll
        for (int i = 0; i < 8; ++i) {
            const float wv = conv_w[(o0 + i) * 64 + c];   // uniform -> s_load
            acc[i][0] += wv * xv.x;
            acc[i][1] += wv * xv.y;
        }
    }

    #pragma unroll
    for (int i = 0; i < 8; ++i) {
        float2 r;
        r.x = fmaxf(acc[i][0] * au[i] + bu[i], 0.f);
        r.y = fmaxf(acc[i][1] * au[i] + bu[i], 0.f);
        *reinterpret_cast<float2*>(out + ((size_t)(b * 64 + o0 + i)) * N_ + n0 + nn) = r;
    }
}

extern "C" void kernel_launch(void* const* d_in, const int* in_sizes, int n_in,
                              void* d_out, int out_size, void* d_ws, size_t ws_size,
                              hipStream_t stream) {
    (void)in_sizes; (void)n_in; (void)out_size; (void)ws_size;
    const float* x      = (const float*)d_in[0];
    const float* w      = (const float*)d_in[1];
    const float* conv_w = (const float*)d_in[2];
    const float* conv_b = (const float*)d_in[3];
    const float* gamma  = (const float*)d_in[4];
    const float* beta   = (const float*)d_in[5];
    float* out = (float*)d_out;
    float* ws  = (float*)d_ws;

    // no memset needed: every ws word consumed is produced this call
    k_gram<<<dim3(NT_ + 1, B_), 256, 0, stream>>>(x, w, ws);
    k_reduce<<<64, 256, 0, stream>>>(ws);
    k_finalize<<<64, 256, 0, stream>>>(conv_w, conv_b, gamma, beta, ws);
    k_main<<<dim3(32, B_), 512, 0, stream>>>(x, conv_w, ws, out);
}

// Round 5
// 85.697 us; speedup vs baseline: 1.8644x; 1.2060x over previous
//
#include <hip/hip_runtime.h>
#include <math.h>

#define B_ 8
#define C_ 64
#define N_ 4096
#define NT_ 32   // n-tiles (128 wide)

// ws float offsets
#define M_OFF   0                          // M[b][o][n] = (W x)  (8 MB)
#define SMP_OFF (B_ * C_ * N_)             // SMp[tile][b][o]  (32*8*64)
#define SQP_OFF (SMP_OFF + NT_ * B_ * C_)  // SQp[tile][b][o]
#define SS_OFF  (SQP_OFF + NT_ * B_ * C_)  // sS[b]
#define SC_OFF  (SS_OFF + B_)              // sScale[b] = 1/(N*s+1)
#define A_OFF   (SC_OFF + B_)              // a[b][o]
#define BB_OFF  (A_OFF + B_ * C_)          // bb[b][o]

// ---------------------------------------------------------------------------
// K1: M[b,o,n] = sum_c W[o,c] x[b,c,n]; per-tile partials SMp = sum_n M,
// SQp = sum_n M^2. grid (33, 8): x<32 = 128-wide n-tile, x==32 = fused
// per-batch scales block. 512 threads (8 waves; wave w owns o in [8w,8w+8)).
// ---------------------------------------------------------------------------
__global__ __launch_bounds__(512) void k_conv(const float* __restrict__ x,
                                              const float* __restrict__ wvec,
                                              const float* __restrict__ conv_w,
                                              float* __restrict__ ws) {
    const int b = blockIdx.y;
    const int t = threadIdx.x;

    __shared__ float xsm[64 * 128];   // [c][n] 32 KB

    if (blockIdx.x == NT_) {
        // fused scales: s_b = sum relu(tanh(w))^2
        const float4* wb = reinterpret_cast<const float4*>(wvec + (size_t)b * N_);
        float p = 0.f;
        #pragma unroll
        for (int i = 0; i < 2; ++i) {
            const float4 v = wb[t + i * 512];
            const float vv[4] = {v.x, v.y, v.z, v.w};
            #pragma unroll
            for (int j = 0; j < 4; ++j)
                if (vv[j] > 0.f) { const float th = tanhf(vv[j]); p += th * th; }
        }
        #pragma unroll
        for (int m = 32; m >= 1; m >>= 1) p += __shfl_xor(p, m);
        if ((t & 63) == 0) xsm[t >> 6] = p;
        __syncthreads();
        if (t == 0) {
            float s = 0.f;
            #pragma unroll
            for (int wv2 = 0; wv2 < 8; ++wv2) s += xsm[wv2];
            ws[SS_OFF + b] = s;
            ws[SC_OFF + b] = 1.f / ((float)N_ * s + 1.f);
        }
        return;
    }

    const int tile = blockIdx.x;
    const int n0 = tile * 128;
    const float* xb = x + (size_t)b * C_ * N_ + n0;

    // stage x tile (coalesced float4; stores along n are conflict-free)
    const int k0 = (t & 31) * 4;
    #pragma unroll
    for (int it = 0; it < 4; ++it) {
        const int cc = it * 16 + (t >> 5);
        *reinterpret_cast<float4*>(&xsm[cc * 128 + k0]) =
            *reinterpret_cast<const float4*>(xb + (size_t)cc * N_ + k0);
    }
    __syncthreads();

    const int o0 = __builtin_amdgcn_readfirstlane((t >> 6) * 8);  // wave-uniform
    const int nn = (t & 63) * 2;

    float acc[8][2] = {};
    #pragma unroll 4
    for (int c = 0; c < 64; ++c) {
        const float2 xv = *reinterpret_cast<const float2*>(&xsm[c * 128 + nn]);
        #pragma unroll
        for (int i = 0; i < 8; ++i) {
            const float wv = conv_w[(o0 + i) * 64 + c];   // uniform -> s_load
            acc[i][0] += wv * xv.x;
            acc[i][1] += wv * xv.y;
        }
    }

    // write M + wave-reduce partial sums
    #pragma unroll
    for (int i = 0; i < 8; ++i) {
        const int o = o0 + i;
        *reinterpret_cast<float2*>(ws + M_OFF + ((size_t)(b * 64 + o)) * N_ + n0 + nn) =
            make_float2(acc[i][0], acc[i][1]);
        float s = acc[i][0] + acc[i][1];
        float q = acc[i][0] * acc[i][0] + acc[i][1] * acc[i][1];
        #pragma unroll
        for (int m = 32; m >= 1; m >>= 1) {
            s += __shfl_xor(s, m);
            q += __shfl_xor(q, m);
        }
        if ((t & 63) == 0) {
            ws[SMP_OFF + (tile * B_ + b) * C_ + o] = s;
            ws[SQP_OFF + (tile * B_ + b) * C_ + o] = q;
        }
    }
}

// ---------------------------------------------------------------------------
// K2: reduce partials + BN stats -> per-(b,o) affine (a, bb).
// ONE block, 512 threads: thread t owns (b = t>>6, o = t&63).
// ---------------------------------------------------------------------------
__global__ __launch_bounds__(512) void k_stats(const float* __restrict__ conv_b,
                                               const float* __restrict__ gamma,
                                               const float* __restrict__ beta,
                                               float* __restrict__ ws) {
    const int t = threadIdx.x;
    const int b = t >> 6, o = t & 63;

    __shared__ float sTs[8][64], sTq[8][64];
    __shared__ float sAl[64], sMe[64];

    float SM = 0.f, SQ = 0.f;
    #pragma unroll 8
    for (int p = 0; p < NT_; ++p) {
        SM += ws[SMP_OFF + (p * B_ + b) * C_ + o];
        SQ += ws[SQP_OFF + (p * B_ + b) * C_ + o];
    }
    const float sS = ws[SS_OFF + b];
    const float sc = ws[SC_OFF + b];
    const float q  = sS * sc * SM + conv_b[o];       // per-(b,o) constant
    // y = sc*M + q;  Sum_n y and Sum_n y^2:
    sTs[b][o] = sc * SM + 4096.f * q;
    sTq[b][o] = sc * sc * SQ + 2.f * sc * q * SM + 4096.f * q * q;
    __syncthreads();

    if (t < 64) {
        float Sy = 0.f, Syy = 0.f;
        #pragma unroll
        for (int bb2 = 0; bb2 < 8; ++bb2) { Sy += sTs[bb2][t]; Syy += sTq[bb2][t]; }
        const float mean = Sy / 32768.f;
        const float var  = Syy / 32768.f - mean * mean;
        sAl[t] = gamma[t] * rsqrtf(var + 1e-5f);
        sMe[t] = mean;
    }
    __syncthreads();

    const float alpha = sAl[o];
    ws[A_OFF  + b * 64 + o] = sc * alpha;
    ws[BB_OFF + b * 64 + o] = (q - sMe[o]) * alpha + beta[o];
}

// ---------------------------------------------------------------------------
// K3: out = relu(a[b,o] * M + bb[b,o]). Pure elementwise, float4.
// grid 1024 x 256 threads, 2 float4 per thread.
// ---------------------------------------------------------------------------
__global__ __launch_bounds__(256) void k_emit(const float* __restrict__ ws,
                                              float* __restrict__ out) {
    const int idx = blockIdx.x * 256 + threadIdx.x;
    #pragma unroll
    for (int h = 0; h < 2; ++h) {
        const int e = idx + h * (1024 * 256);       // float4 index, < 524288
        const int row = e >> 10;                    // (b*64+o), 1024 float4/row
        const float a  = ws[A_OFF + row];
        const float bb = ws[BB_OFF + row];
        const float4 m = *reinterpret_cast<const float4*>(ws + M_OFF + (size_t)e * 4);
        float4 r;
        r.x = fmaxf(m.x * a + bb, 0.f);
        r.y = fmaxf(m.y * a + bb, 0.f);
        r.z = fmaxf(m.z * a + bb, 0.f);
        r.w = fmaxf(m.w * a + bb, 0.f);
        *reinterpret_cast<float4*>(out + (size_t)e * 4) = r;
    }
}

extern "C" void kernel_launch(void* const* d_in, const int* in_sizes, int n_in,
                              void* d_out, int out_size, void* d_ws, size_t ws_size,
                              hipStream_t stream) {
    (void)in_sizes; (void)n_in; (void)out_size; (void)ws_size;
    const float* x      = (const float*)d_in[0];
    const float* w      = (const float*)d_in[1];
    const float* conv_w = (const float*)d_in[2];
    const float* conv_b = (const float*)d_in[3];
    const float* gamma  = (const float*)d_in[4];
    const float* beta   = (const float*)d_in[5];
    float* out = (float*)d_out;
    float* ws  = (float*)d_ws;

    // every ws word consumed is produced this call: no memset needed
    k_conv<<<dim3(NT_ + 1, B_), 512, 0, stream>>>(x, w, conv_w, ws);
    k_stats<<<1, 512, 0, stream>>>(conv_b, gamma, beta, ws);
    k_emit<<<1024, 256, 0, stream>>>(ws, out);
}